// Round 3
// baseline (1478.929 us; speedup 1.0000x reference)
//
#include <hip/hip_runtime.h>
#include <stdint.h>

#define BTOT 7200
#define EPSV 1e-5f

using bf16x8 = __attribute__((ext_vector_type(8))) __bf16;
using f32x4  = __attribute__((ext_vector_type(4))) float;

#define GLD16(gp, lp) __builtin_amdgcn_global_load_lds( \
    (const __attribute__((address_space(1))) uint32_t*)(gp), \
    (__attribute__((address_space(3))) uint32_t*)(lp), 16, 0, 0)

// XOR bank swizzle within a [64 rows][128B] half-unit; keeps 16B groups intact.
// Verified on HW in round-2 (SQ_LDS_BANK_CONFLICT == 0, correctness passed).
__device__ __forceinline__ int swz(int d, int bir){ return (d*128 + bir) ^ ((d&7)<<4); }

// ---------------------------------------------------------------------------
// ws layout (bytes) — 59,547,648 total (round-1/2 proven fit)
//   [0, 33554432)          stageA units: 2048 = (k 512 x eg 4), 16KB each
//   [33554432, 50331648)   stageB units: 1024 = (d 64 x q 4 x eg 4), 16KB each
//   [50331648, 52174848)   f1: 7200 x 64 f32
//   [52174848, 59547648)   f2: 7200 x 256 f32
// Unit = [hl 2][row 64][e 64] bf16 (16KB), rows XOR-swizzled.
// ---------------------------------------------------------------------------

__global__ __launch_bounds__(256) void prep_convert(const float* __restrict__ Wpre,
    const float* __restrict__ Waft, __bf16* __restrict__ dst)
{
  int g = (int)blockIdx.x*256 + (int)threadIdx.x;
  const float* src; char* ubase; int sb;
  if (g < 2048*512){
    int u = g>>9, r = g&511;
    int k = u>>2, eg = u&3, d = r>>3, oc = r&7;
    src = Wpre + ((size_t)(k*64 + d))*256 + eg*64 + oc*8;
    ubase = (char*)dst + (size_t)u*16384;
    sb = swz(d, oc*16);
  } else {
    int g2 = g - 2048*512;
    int u = g2>>9, r = g2&511;
    int dd = u>>4, q = (u>>2)&3, eg = u&3, j = r>>3, oc = r&7;
    src = Waft + ((size_t)(dd*256 + q*64 + j))*256 + eg*64 + oc*8;
    ubase = (char*)dst + (size_t)(2048 + u)*16384;
    sb = swz(j, oc*16);
  }
  float4 x0 = *(const float4*)src, x1 = *(const float4*)(src + 4);
  float xs[8] = {x0.x,x0.y,x0.z,x0.w,x1.x,x1.y,x1.z,x1.w};
  bf16x8 hi, lo;
#pragma unroll
  for (int e = 0; e < 8; e++){
    __bf16 h = (__bf16)xs[e]; hi[e] = h; lo[e] = (__bf16)(xs[e] - (float)h);
  }
  *(bf16x8*)(ubase + sb) = hi;
  *(bf16x8*)(ubase + 8192 + sb) = lo;
}

// ---------------------------------------------------------------------------
// bias GEMVs initialize f1/f2 (WRITE, not add) so stages can atomicAdd on top.
// ---------------------------------------------------------------------------
__global__ __launch_bounds__(256) void biasA(const float* __restrict__ feats,
    const float* __restrict__ bp, float* __restrict__ f1)
{
  const int t = (int)threadIdx.x, d = t&63, bq = t>>6;
  const int b0 = (int)blockIdx.x*32 + bq*8;
  float acc[8] = {};
  for (int k = 0; k < 512; k++){
    float wv = bp[k*64 + d];
#pragma unroll
    for (int j = 0; j < 8; j++) acc[j] = fmaf(feats[(size_t)(b0+j)*512 + k], wv, acc[j]);
  }
#pragma unroll
  for (int j = 0; j < 8; j++) f1[(size_t)(b0+j)*64 + d] = acc[j];
}

__global__ __launch_bounds__(1024) void biasB(const float* __restrict__ fln1,
    const float* __restrict__ ba, float* __restrict__ f2)
{
  const int t = (int)threadIdx.x, eo = t&255, bq = t>>8;
  const int b0 = (int)blockIdx.x*32 + bq*8;
  float acc[8] = {};
  for (int d = 0; d < 64; d++){
    float wv = ba[d*256 + eo];
#pragma unroll
    for (int j = 0; j < 8; j++) acc[j] = fmaf(fln1[(size_t)(b0+j)*64 + d], wv, acc[j]);
  }
#pragma unroll
  for (int j = 0; j < 8; j++) f2[(size_t)(b0+j)*256 + eo] = acc[j];
}

// ---------------------------------------------------------------------------
// Fused dynamic-GEMM stage (round-3):
//   out[b, col] += sum_sg wv[b,sg] * ( sum_e q[b,e] * W[sg-row, e] ), bf16x3.
// 4 waves/block (dg = wave = 16 output rows of the 64-row unit), 8 bt = 128 b.
// dbuf 2 x 32KB (2 subs each), ONE __syncthreads per 32KB (m97-proven shape);
// 64KB LDS + ~230 VGPR -> 2 blocks/CU so the barrier drain is covered by the
// partner block's MFMA phase.  No manual vmcnt (round-2 lesson).
// ---------------------------------------------------------------------------
#define MMPASS(AF, QARR, KS) \
  _Pragma("unroll") for (int bt = 0; bt < 8; bt++) \
    c[bt] = __builtin_amdgcn_mfma_f32_16x16x32_bf16(AF, QARR[bt][KS], c[bt], 0,0,0);

#define COMPUTE_SUB(LOFF, SG) { \
  float wv[8]; \
  _Pragma("unroll") for (int bt = 0; bt < 8; bt++) wv[bt] = wvsrc[rowc[bt] + (SG)]; \
  const char* Bp = lds + (LOFF); \
  bf16x8 h0  = *(const bf16x8*)(Bp + ra0); \
  bf16x8 h1  = *(const bf16x8*)(Bp + ra1); \
  bf16x8 lo0 = *(const bf16x8*)(Bp + 8192 + ra0); \
  bf16x8 lo1 = *(const bf16x8*)(Bp + 8192 + ra1); \
  f32x4 c[8] = {}; \
  __builtin_amdgcn_s_setprio(1); \
  MMPASS(h0,  qh, 0) MMPASS(h1,  qh, 1) \
  MMPASS(h0,  ql, 0) MMPASS(h1,  ql, 1) \
  MMPASS(lo0, qh, 0) MMPASS(lo1, qh, 1) \
  __builtin_amdgcn_s_setprio(0); \
  _Pragma("unroll") for (int bt = 0; bt < 8; bt++) acc[bt] += wv[bt]*c[bt]; }

#define STAGE2(LOFF, S0) { \
  _Pragma("unroll") for (int s = 0; s < 2; s++){ \
    const char* us = wub + (size_t)(u0 + ((S0)+s)*ustep)*16384; \
    _Pragma("unroll") for (int j = 0; j < 4; j++) \
      GLD16(us + j*4096 + t*16, lds + (LOFF) + s*16384 + j*4096 + t*16); } }

template<int STAGE>
__global__ __launch_bounds__(256, 2) void stage_fused(
    const float* __restrict__ query, const float* __restrict__ wvsrc,
    const __bf16* __restrict__ Wu, float* __restrict__ outp)
{
  __shared__ __align__(16) char lds[65536];
  const int t = (int)threadIdx.x, dg = t>>6, lane = t&63, l15 = lane&15, l4 = lane>>4;

  int eg, NS, ustep, u0, wvstride, wvoff, orow, ocol;
  if (STAGE == 0){              // bid = btile*8 + js*4 + eg ; grid 57*8 = 456
    int sub = (int)blockIdx.x & 7; int js = sub>>2; eg = sub&3;
    NS = 256; ustep = 4; u0 = js*1024 + eg;
    wvstride = 512; wvoff = js*256; orow = 64; ocol = 0;
  } else {                      // bid = btile*16 + qq*4 + eg ; grid 57*16 = 912
    int sub = (int)blockIdx.x & 15; int qq = sub>>2; eg = sub&3;
    NS = 64; ustep = 16; u0 = qq*4 + eg;
    wvstride = 64; wvoff = 0; orow = 256; ocol = qq*64;
  }
  const int btile = (int)blockIdx.x >> (STAGE == 0 ? 3 : 4);
  const int b0 = btile*128;
  const int eb = eg*64;

  // persistent q B-fragments (hi/lo) + wv row bases
  bf16x8 qh[8][2], ql[8][2];
  int rowc[8];
#pragma unroll
  for (int bt = 0; bt < 8; bt++){
    int b = b0 + bt*16 + l15;
    bool v = b < BTOT;
    int bc = v ? b : (BTOT-1);
    rowc[bt] = bc*wvstride + wvoff;
    const float* qp = query + (size_t)b*256 + eb + l4*8;
#pragma unroll
    for (int ks = 0; ks < 2; ks++){
      float xs[8];
      if (v){
        float4 xa = *(const float4*)(qp + ks*32);
        float4 xb = *(const float4*)(qp + ks*32 + 4);
        xs[0]=xa.x; xs[1]=xa.y; xs[2]=xa.z; xs[3]=xa.w;
        xs[4]=xb.x; xs[5]=xb.y; xs[6]=xb.z; xs[7]=xb.w;
      } else {
#pragma unroll
        for (int e = 0; e < 8; e++) xs[e] = 0.f;
      }
#pragma unroll
      for (int e = 0; e < 8; e++){
        __bf16 h = (__bf16)xs[e];
        qh[bt][ks][e] = h;
        ql[bt][ks][e] = (__bf16)(xs[e] - (float)h);
      }
    }
  }

  const int ra0 = swz(dg*16 + l15, l4*16);
  const int ra1 = swz(dg*16 + l15, 64 + l4*16);
  const char* wub = (const char*)Wu;
  f32x4 acc[8] = {};

  STAGE2(0, 0)
  for (int s0 = 0; s0 < NS; s0 += 4){
    __syncthreads();                       // buf0 (s0,s0+1) drained; buf1 free
    STAGE2(32768, s0+2)
    COMPUTE_SUB(0, s0)
    COMPUTE_SUB(16384, s0+1)
    __syncthreads();                       // buf1 drained; buf0 free
    if (s0 + 4 < NS) STAGE2(0, s0+4)
    COMPUTE_SUB(32768, s0+2)
    COMPUTE_SUB(49152, s0+3)
  }

  // epilogue: atomic accumulate partials
#pragma unroll
  for (int bt = 0; bt < 8; bt++){
    int b = b0 + bt*16 + l15;
    if (b < BTOT){
      float* op = outp + (size_t)b*orow + ocol + dg*16 + l4*4;
#pragma unroll
      for (int i = 0; i < 4; i++) atomicAdd(op + i, acc[bt][i]);
    }
  }
}

// ---------------------------------------------------------------------------
// In-place LayerNorm + ReLU, one wave per row. WID = 64 or 256.
// ---------------------------------------------------------------------------
template<int WID>
__global__ void ln_relu(float* __restrict__ x, const float* __restrict__ gamma,
                        const float* __restrict__ beta)
{
  const int wv = (int)threadIdx.x >> 6, lane = (int)threadIdx.x & 63;
  const int row = (int)blockIdx.x*4 + wv;
  if (row >= BTOT) return;
  float* xr = x + (size_t)row * WID;
  constexpr int PER = WID / 64;
  float v[PER];
  if constexpr (PER == 1){
    v[0] = xr[lane];
  } else {
    float4 tq = *(const float4*)(xr + lane*4);
    v[0]=tq.x; v[1]=tq.y; v[2]=tq.z; v[3]=tq.w;
  }
  float s = 0.f, sq = 0.f;
#pragma unroll
  for (int p = 0; p < PER; p++){ s += v[p]; sq += v[p]*v[p]; }
#pragma unroll
  for (int off = 32; off > 0; off >>= 1){
    s  += __shfl_xor(s, off);
    sq += __shfl_xor(sq, off);
  }
  const float mu = s * (1.f/WID);
  const float var = sq * (1.f/WID) - mu*mu;
  const float rs = rsqrtf(var + EPSV);
#pragma unroll
  for (int p = 0; p < PER; p++){
    const int col = (PER == 1) ? lane : lane*4 + p;
    const float y = (v[p] - mu)*rs*gamma[col] + beta[col];
    v[p] = fmaxf(y, 0.f);
  }
  if constexpr (PER == 1){ xr[lane] = v[0]; }
  else {
    float4 tq; tq.x=v[0]; tq.y=v[1]; tq.z=v[2]; tq.w=v[3];
    *(float4*)(xr + lane*4) = tq;
  }
}

// ---------------------------------------------------------------------------
// Stage C: out = relu(LN3(fln2 @ W_out^T + b_out)). 16 rows / WG, fp32 vector.
// (reshape in the reference is a flat reinterpret -> row map is identity;
//  empirically confirmed by rounds 1-2 passing.)
// ---------------------------------------------------------------------------
__global__ __launch_bounds__(256) void stageC(
    const float* __restrict__ fln2, const float* __restrict__ Wout,
    const float* __restrict__ bout, const float* __restrict__ g3,
    const float* __restrict__ be3, float* __restrict__ out)
{
  __shared__ float xt[16][256];
  __shared__ float yt[16][256];
  const int t = (int)threadIdx.x;
  const int r0 = (int)blockIdx.x * 16;
#pragma unroll
  for (int i = 0; i < 16; i++) xt[i][t] = fln2[(size_t)(r0 + i)*256 + t];
  __syncthreads();
  const int lane = t & 63, wv = t >> 6;

  for (int ec = 0; ec < 4; ec++){
    const int e = ec*64 + lane;
    const float* wr = Wout + (size_t)e * 256;
    float a0=0.f, a1=0.f, a2=0.f, a3=0.f;
#pragma unroll 8
    for (int k4 = 0; k4 < 64; k4++){
      float4 wq = *(const float4*)(wr + k4*4);
      float4 x0 = *(const float4*)&xt[wv     ][k4*4];
      float4 x1 = *(const float4*)&xt[wv +  4][k4*4];
      float4 x2 = *(const float4*)&xt[wv +  8][k4*4];
      float4 x3 = *(const float4*)&xt[wv + 12][k4*4];
      a0 += x0.x*wq.x + x0.y*wq.y + x0.z*wq.z + x0.w*wq.w;
      a1 += x1.x*wq.x + x1.y*wq.y + x1.z*wq.z + x1.w*wq.w;
      a2 += x2.x*wq.x + x2.y*wq.y + x2.z*wq.z + x2.w*wq.w;
      a3 += x3.x*wq.x + x3.y*wq.y + x3.z*wq.z + x3.w*wq.w;
    }
    const float bb = bout[e];
    yt[wv     ][e] = a0 + bb;
    yt[wv +  4][e] = a1 + bb;
    yt[wv +  8][e] = a2 + bb;
    yt[wv + 12][e] = a3 + bb;
  }
  __syncthreads();

#pragma unroll
  for (int rr = 0; rr < 4; rr++){
    const int row = wv + rr*4;
    float4 v = *(const float4*)&yt[row][lane*4];
    float s  = v.x + v.y + v.z + v.w;
    float sq = v.x*v.x + v.y*v.y + v.z*v.z + v.w*v.w;
#pragma unroll
    for (int off = 32; off > 0; off >>= 1){
      s  += __shfl_xor(s, off);
      sq += __shfl_xor(sq, off);
    }
    const float mu = s * (1.f/256.f);
    const float var = sq * (1.f/256.f) - mu*mu;
    const float rs = rsqrtf(var + EPSV);
    const int c0 = lane*4;
    float4 o;
    o.x = fmaxf((v.x - mu)*rs*g3[c0  ] + be3[c0  ], 0.f);
    o.y = fmaxf((v.y - mu)*rs*g3[c0+1] + be3[c0+1], 0.f);
    o.z = fmaxf((v.z - mu)*rs*g3[c0+2] + be3[c0+2], 0.f);
    o.w = fmaxf((v.w - mu)*rs*g3[c0+3] + be3[c0+3], 0.f);
    *(float4*)(out + (size_t)(r0 + row)*256 + c0) = o;
  }
}

// ---------------------------------------------------------------------------
extern "C" void kernel_launch(void* const* d_in, const int* in_sizes, int n_in,
                              void* d_out, int out_size, void* d_ws, size_t ws_size,
                              hipStream_t stream)
{
  (void)in_sizes; (void)n_in; (void)out_size; (void)ws_size;
  const float* query = (const float*)d_in[0];
  const float* feats = (const float*)d_in[1];
  const float* Wpre  = (const float*)d_in[2];
  const float* bpre  = (const float*)d_in[3];
  const float* Waft  = (const float*)d_in[4];
  const float* baft  = (const float*)d_in[5];
  const float* Wout  = (const float*)d_in[6];
  const float* bout  = (const float*)d_in[7];
  const float* g1  = (const float*)d_in[8];
  const float* be1 = (const float*)d_in[9];
  const float* g2  = (const float*)d_in[10];
  const float* be2 = (const float*)d_in[11];
  const float* g3  = (const float*)d_in[12];
  const float* be3 = (const float*)d_in[13];
  float* outp = (float*)d_out;

  __bf16* wconv = (__bf16*)d_ws;                       // 50,331,648 B (A+B units)
  float* f1 = (float*)((char*)d_ws + 50331648);        // 1,843,200 B
  float* f2 = (float*)((char*)d_ws + 52174848);        // 7,372,800 B

  prep_convert<<<6144, 256, 0, stream>>>(Wpre, Waft, wconv);
  biasA<<<225, 256, 0, stream>>>(feats, bpre, f1);
  stage_fused<0><<<456, 256, 0, stream>>>(query, feats, wconv, f1);
  ln_relu<64><<<1800, 256, 0, stream>>>(f1, g1, be1);
  biasB<<<225, 1024, 0, stream>>>(f1, baft, f2);
  stage_fused<1><<<912, 256, 0, stream>>>(query, f1, wconv + (size_t)2048*8192, f2);
  ln_relu<256><<<1800, 256, 0, stream>>>(f2, g2, be2);
  stageC<<<450, 256, 0, stream>>>(f2, Wout, bout, g3, be3, outp);
}

// Round 4
// 873.271 us; speedup vs baseline: 1.6936x; 1.6936x over previous
//
#include <hip/hip_runtime.h>
#include <stdint.h>

#define BTOT 7200
#define EPSV 1e-5f

using bf16x8 = __attribute__((ext_vector_type(8))) __bf16;
using f32x4  = __attribute__((ext_vector_type(4))) float;

#define GLD16(gp, lp) __builtin_amdgcn_global_load_lds( \
    (const __attribute__((address_space(1))) uint32_t*)(gp), \
    (__attribute__((address_space(3))) uint32_t*)(lp), 16, 0, 0)

// XOR bank swizzle within a [64 rows][128B] half-unit; keeps 16B groups intact.
// HW-verified rounds 1-3 (SQ_LDS_BANK_CONFLICT == 0, correctness passed).
__device__ __forceinline__ int swz(int d, int bir){ return (d*128 + bir) ^ ((d&7)<<4); }

// ---------------------------------------------------------------------------
// ws layout (bytes) — 59,547,648 total (rounds 1-3 proven fit)
//   [0, 33554432)          stageA units: 2048 = (k 512 x eg 4), 16KB each
//   [33554432, 50331648)   stageB units: 1024 = (d 64 x q 4 x eg 4), 16KB each
//   [50331648, 52174848)   f1: 7200 x 64 f32
//   [52174848, 59547648)   f2: 7200 x 256 f32
// Unit = [hl 2][row 64][e 64] bf16 (16KB), rows XOR-swizzled.
// ---------------------------------------------------------------------------

__global__ __launch_bounds__(256) void prep_convert(const float* __restrict__ Wpre,
    const float* __restrict__ Waft, __bf16* __restrict__ dst)
{
  int g = (int)blockIdx.x*256 + (int)threadIdx.x;
  const float* src; char* ubase; int sb;
  if (g < 2048*512){
    int u = g>>9, r = g&511;
    int k = u>>2, eg = u&3, d = r>>3, oc = r&7;
    src = Wpre + ((size_t)(k*64 + d))*256 + eg*64 + oc*8;
    ubase = (char*)dst + (size_t)u*16384;
    sb = swz(d, oc*16);
  } else {
    int g2 = g - 2048*512;
    int u = g2>>9, r = g2&511;
    int dd = u>>4, q = (u>>2)&3, eg = u&3, j = r>>3, oc = r&7;
    src = Waft + ((size_t)(dd*256 + q*64 + j))*256 + eg*64 + oc*8;
    ubase = (char*)dst + (size_t)(2048 + u)*16384;
    sb = swz(j, oc*16);
  }
  float4 x0 = *(const float4*)src, x1 = *(const float4*)(src + 4);
  float xs[8] = {x0.x,x0.y,x0.z,x0.w,x1.x,x1.y,x1.z,x1.w};
  bf16x8 hi, lo;
#pragma unroll
  for (int e = 0; e < 8; e++){
    __bf16 h = (__bf16)xs[e]; hi[e] = h; lo[e] = (__bf16)(xs[e] - (float)h);
  }
  *(bf16x8*)(ubase + sb) = hi;
  *(bf16x8*)(ubase + 8192 + sb) = lo;
}

// ---------------------------------------------------------------------------
// bias GEMVs initialize f1/f2 (WRITE, not add) so stages can atomicAdd on top.
// ---------------------------------------------------------------------------
__global__ __launch_bounds__(256) void biasA(const float* __restrict__ feats,
    const float* __restrict__ bp, float* __restrict__ f1)
{
  const int t = (int)threadIdx.x, d = t&63, bq = t>>6;
  const int b0 = (int)blockIdx.x*32 + bq*8;
  float acc[8] = {};
  for (int k = 0; k < 512; k++){
    float wv = bp[k*64 + d];
#pragma unroll
    for (int j = 0; j < 8; j++) acc[j] = fmaf(feats[(size_t)(b0+j)*512 + k], wv, acc[j]);
  }
#pragma unroll
  for (int j = 0; j < 8; j++) f1[(size_t)(b0+j)*64 + d] = acc[j];
}

__global__ __launch_bounds__(1024) void biasB(const float* __restrict__ fln1,
    const float* __restrict__ ba, float* __restrict__ f2)
{
  const int t = (int)threadIdx.x, eo = t&255, bq = t>>8;
  const int b0 = (int)blockIdx.x*32 + bq*8;
  float acc[8] = {};
  for (int d = 0; d < 64; d++){
    float wv = ba[d*256 + eo];
#pragma unroll
    for (int j = 0; j < 8; j++) acc[j] = fmaf(fln1[(size_t)(b0+j)*64 + d], wv, acc[j]);
  }
#pragma unroll
  for (int j = 0; j < 8; j++) f2[(size_t)(b0+j)*256 + eo] = acc[j];
}

// ---------------------------------------------------------------------------
// Fused dynamic-GEMM stage (round-4):
//   out[b, col] += sum_sg wv[b,sg] * ( sum_e q[b,e] * W[sg-row, e] ), bf16x3.
// 4 waves/block (dg = wave), bt=4 -> 64 b-rows/block.  Register budget ~145
// (frags 64 + acc 16 + c 16 + A-frags 16 + misc) -> NO SPILL (round-3 lesson:
// bt=8's 240-reg demand spilled to scratch = 1.4 GB of L2/HBM traffic).
// dbuf 2 x 32KB, one __syncthreads per 32KB; 64KB LDS + <=256 VGPR ->
// 2 blocks/CU so barrier drains overlap with the partner block's MFMA.
// ---------------------------------------------------------------------------
#define MMPASS(AF, QARR, KS) \
  _Pragma("unroll") for (int bt = 0; bt < 4; bt++) \
    c[bt] = __builtin_amdgcn_mfma_f32_16x16x32_bf16(AF, QARR[bt][KS], c[bt], 0,0,0);

#define COMPUTE_SUB(LOFF, SG) { \
  float wv[4]; \
  _Pragma("unroll") for (int bt = 0; bt < 4; bt++) wv[bt] = wvsrc[rowc[bt] + (SG)]; \
  const char* Bp = lds + (LOFF); \
  bf16x8 h0  = *(const bf16x8*)(Bp + ra0); \
  bf16x8 h1  = *(const bf16x8*)(Bp + ra1); \
  bf16x8 lo0 = *(const bf16x8*)(Bp + 8192 + ra0); \
  bf16x8 lo1 = *(const bf16x8*)(Bp + 8192 + ra1); \
  f32x4 c[4] = {}; \
  __builtin_amdgcn_s_setprio(1); \
  MMPASS(h0,  qh, 0) MMPASS(h1,  qh, 1) \
  MMPASS(h0,  ql, 0) MMPASS(h1,  ql, 1) \
  MMPASS(lo0, qh, 0) MMPASS(lo1, qh, 1) \
  __builtin_amdgcn_s_setprio(0); \
  _Pragma("unroll") for (int bt = 0; bt < 4; bt++) acc[bt] += wv[bt]*c[bt]; }

#define STAGE2(LOFF, S0) { \
  _Pragma("unroll") for (int s = 0; s < 2; s++){ \
    const char* us = wub + (size_t)(u0 + ((S0)+s)*ustep)*16384; \
    _Pragma("unroll") for (int j = 0; j < 4; j++) \
      GLD16(us + j*4096 + t*16, lds + (LOFF) + s*16384 + j*4096 + t*16); } }

template<int STAGE>
__global__ __launch_bounds__(256, 2) void stage_fused(
    const float* __restrict__ query, const float* __restrict__ wvsrc,
    const __bf16* __restrict__ Wu, float* __restrict__ outp)
{
  __shared__ __align__(16) char lds[65536];
  const int t = (int)threadIdx.x, dg = t>>6, lane = t&63, l15 = lane&15, l4 = lane>>4;

  int eg, NS, ustep, u0, wvstride, wvoff, orow, ocol;
  if (STAGE == 0){              // bid = btile*8 + js*4 + eg ; grid 113*8 = 904
    int sub = (int)blockIdx.x & 7; int js = sub>>2; eg = sub&3;
    NS = 256; ustep = 4; u0 = js*1024 + eg;
    wvstride = 512; wvoff = js*256; orow = 64; ocol = 0;
  } else {                      // bid = btile*16 + qq*4 + eg ; grid 113*16 = 1808
    int sub = (int)blockIdx.x & 15; int qq = sub>>2; eg = sub&3;
    NS = 64; ustep = 16; u0 = qq*4 + eg;
    wvstride = 64; wvoff = 0; orow = 256; ocol = qq*64;
  }
  const int btile = (int)blockIdx.x >> (STAGE == 0 ? 3 : 4);
  const int b0 = btile*64;
  const int eb = eg*64;

  // persistent q B-fragments (hi/lo), 4 b-tiles -> 64 VGPRs
  bf16x8 qh[4][2], ql[4][2];
  int rowc[4];
#pragma unroll
  for (int bt = 0; bt < 4; bt++){
    int b = b0 + bt*16 + l15;
    bool v = b < BTOT;
    int bc = v ? b : (BTOT-1);
    rowc[bt] = bc*wvstride + wvoff;
    const float* qp = query + (size_t)b*256 + eb + l4*8;
#pragma unroll
    for (int ks = 0; ks < 2; ks++){
      float xs[8];
      if (v){
        float4 xa = *(const float4*)(qp + ks*32);
        float4 xb = *(const float4*)(qp + ks*32 + 4);
        xs[0]=xa.x; xs[1]=xa.y; xs[2]=xa.z; xs[3]=xa.w;
        xs[4]=xb.x; xs[5]=xb.y; xs[6]=xb.z; xs[7]=xb.w;
      } else {
#pragma unroll
        for (int e = 0; e < 8; e++) xs[e] = 0.f;
      }
#pragma unroll
      for (int e = 0; e < 8; e++){
        __bf16 h = (__bf16)xs[e];
        qh[bt][ks][e] = h;
        ql[bt][ks][e] = (__bf16)(xs[e] - (float)h);
      }
    }
  }

  const int ra0 = swz(dg*16 + l15, l4*16);
  const int ra1 = swz(dg*16 + l15, 64 + l4*16);
  const char* wub = (const char*)Wu;
  f32x4 acc[4] = {};

  STAGE2(0, 0)
  for (int s0 = 0; s0 < NS; s0 += 4){
    __syncthreads();                       // buf0 (s0,s0+1) staged; buf1 free
    STAGE2(32768, s0+2)
    COMPUTE_SUB(0, s0)
    COMPUTE_SUB(16384, s0+1)
    __syncthreads();                       // buf1 staged; buf0 free
    if (s0 + 4 < NS) STAGE2(0, s0+4)
    COMPUTE_SUB(32768, s0+2)
    COMPUTE_SUB(49152, s0+3)
  }

  // epilogue: atomic accumulate partials
#pragma unroll
  for (int bt = 0; bt < 4; bt++){
    int b = b0 + bt*16 + l15;
    if (b < BTOT){
      float* op = outp + (size_t)b*orow + ocol + dg*16 + l4*4;
#pragma unroll
      for (int i = 0; i < 4; i++) atomicAdd(op + i, acc[bt][i]);
    }
  }
}

// ---------------------------------------------------------------------------
// In-place LayerNorm + ReLU, one wave per row. WID = 64 or 256.
// ---------------------------------------------------------------------------
template<int WID>
__global__ void ln_relu(float* __restrict__ x, const float* __restrict__ gamma,
                        const float* __restrict__ beta)
{
  const int wv = (int)threadIdx.x >> 6, lane = (int)threadIdx.x & 63;
  const int row = (int)blockIdx.x*4 + wv;
  if (row >= BTOT) return;
  float* xr = x + (size_t)row * WID;
  constexpr int PER = WID / 64;
  float v[PER];
  if constexpr (PER == 1){
    v[0] = xr[lane];
  } else {
    float4 tq = *(const float4*)(xr + lane*4);
    v[0]=tq.x; v[1]=tq.y; v[2]=tq.z; v[3]=tq.w;
  }
  float s = 0.f, sq = 0.f;
#pragma unroll
  for (int p = 0; p < PER; p++){ s += v[p]; sq += v[p]*v[p]; }
#pragma unroll
  for (int off = 32; off > 0; off >>= 1){
    s  += __shfl_xor(s, off);
    sq += __shfl_xor(sq, off);
  }
  const float mu = s * (1.f/WID);
  const float var = sq * (1.f/WID) - mu*mu;
  const float rs = rsqrtf(var + EPSV);
#pragma unroll
  for (int p = 0; p < PER; p++){
    const int col = (PER == 1) ? lane : lane*4 + p;
    const float y = (v[p] - mu)*rs*gamma[col] + beta[col];
    v[p] = fmaxf(y, 0.f);
  }
  if constexpr (PER == 1){ xr[lane] = v[0]; }
  else {
    float4 tq; tq.x=v[0]; tq.y=v[1]; tq.z=v[2]; tq.w=v[3];
    *(float4*)(xr + lane*4) = tq;
  }
}

// ---------------------------------------------------------------------------
// Stage C: out = relu(LN3(fln2 @ W_out^T + b_out)). 16 rows / WG, fp32 vector.
// ---------------------------------------------------------------------------
__global__ __launch_bounds__(256) void stageC(
    const float* __restrict__ fln2, const float* __restrict__ Wout,
    const float* __restrict__ bout, const float* __restrict__ g3,
    const float* __restrict__ be3, float* __restrict__ out)
{
  __shared__ float xt[16][256];
  __shared__ float yt[16][256];
  const int t = (int)threadIdx.x;
  const int r0 = (int)blockIdx.x * 16;
#pragma unroll
  for (int i = 0; i < 16; i++) xt[i][t] = fln2[(size_t)(r0 + i)*256 + t];
  __syncthreads();
  const int lane = t & 63, wv = t >> 6;

  for (int ec = 0; ec < 4; ec++){
    const int e = ec*64 + lane;
    const float* wr = Wout + (size_t)e * 256;
    float a0=0.f, a1=0.f, a2=0.f, a3=0.f;
#pragma unroll 8
    for (int k4 = 0; k4 < 64; k4++){
      float4 wq = *(const float4*)(wr + k4*4);
      float4 x0 = *(const float4*)&xt[wv     ][k4*4];
      float4 x1 = *(const float4*)&xt[wv +  4][k4*4];
      float4 x2 = *(const float4*)&xt[wv +  8][k4*4];
      float4 x3 = *(const float4*)&xt[wv + 12][k4*4];
      a0 += x0.x*wq.x + x0.y*wq.y + x0.z*wq.z + x0.w*wq.w;
      a1 += x1.x*wq.x + x1.y*wq.y + x1.z*wq.z + x1.w*wq.w;
      a2 += x2.x*wq.x + x2.y*wq.y + x2.z*wq.z + x2.w*wq.w;
      a3 += x3.x*wq.x + x3.y*wq.y + x3.z*wq.z + x3.w*wq.w;
    }
    const float bb = bout[e];
    yt[wv     ][e] = a0 + bb;
    yt[wv +  4][e] = a1 + bb;
    yt[wv +  8][e] = a2 + bb;
    yt[wv + 12][e] = a3 + bb;
  }
  __syncthreads();

#pragma unroll
  for (int rr = 0; rr < 4; rr++){
    const int row = wv + rr*4;
    float4 v = *(const float4*)&yt[row][lane*4];
    float s  = v.x + v.y + v.z + v.w;
    float sq = v.x*v.x + v.y*v.y + v.z*v.z + v.w*v.w;
#pragma unroll
    for (int off = 32; off > 0; off >>= 1){
      s  += __shfl_xor(s, off);
      sq += __shfl_xor(sq, off);
    }
    const float mu = s * (1.f/256.f);
    const float var = sq * (1.f/256.f) - mu*mu;
    const float rs = rsqrtf(var + EPSV);
    const int c0 = lane*4;
    float4 o;
    o.x = fmaxf((v.x - mu)*rs*g3[c0  ] + be3[c0  ], 0.f);
    o.y = fmaxf((v.y - mu)*rs*g3[c0+1] + be3[c0+1], 0.f);
    o.z = fmaxf((v.z - mu)*rs*g3[c0+2] + be3[c0+2], 0.f);
    o.w = fmaxf((v.w - mu)*rs*g3[c0+3] + be3[c0+3], 0.f);
    *(float4*)(out + (size_t)(r0 + row)*256 + c0) = o;
  }
}

// ---------------------------------------------------------------------------
extern "C" void kernel_launch(void* const* d_in, const int* in_sizes, int n_in,
                              void* d_out, int out_size, void* d_ws, size_t ws_size,
                              hipStream_t stream)
{
  (void)in_sizes; (void)n_in; (void)out_size; (void)ws_size;
  const float* query = (const float*)d_in[0];
  const float* feats = (const float*)d_in[1];
  const float* Wpre  = (const float*)d_in[2];
  const float* bpre  = (const float*)d_in[3];
  const float* Waft  = (const float*)d_in[4];
  const float* baft  = (const float*)d_in[5];
  const float* Wout  = (const float*)d_in[6];
  const float* bout  = (const float*)d_in[7];
  const float* g1  = (const float*)d_in[8];
  const float* be1 = (const float*)d_in[9];
  const float* g2  = (const float*)d_in[10];
  const float* be2 = (const float*)d_in[11];
  const float* g3  = (const float*)d_in[12];
  const float* be3 = (const float*)d_in[13];
  float* outp = (float*)d_out;

  __bf16* wconv = (__bf16*)d_ws;                       // 50,331,648 B (A+B units)
  float* f1 = (float*)((char*)d_ws + 50331648);        // 1,843,200 B
  float* f2 = (float*)((char*)d_ws + 52174848);        // 7,372,800 B

  prep_convert<<<6144, 256, 0, stream>>>(Wpre, Waft, wconv);
  biasA<<<225, 256, 0, stream>>>(feats, bpre, f1);
  stage_fused<0><<<904, 256, 0, stream>>>(query, feats, wconv, f1);
  ln_relu<64><<<1800, 256, 0, stream>>>(f1, g1, be1);
  biasB<<<225, 1024, 0, stream>>>(f1, baft, f2);
  stage_fused<1><<<1808, 256, 0, stream>>>(query, f1, wconv + (size_t)2048*8192, f2);
  ln_relu<256><<<1800, 256, 0, stream>>>(f2, g2, be2);
  stageC<<<450, 256, 0, stream>>>(f2, Wout, bout, g3, be3, outp);
}